// Round 6
// baseline (250.645 us; speedup 1.0000x reference)
//
#include <hip/hip_runtime.h>
#include <stdint.h>

// MultiHeadAttention: x[4,2048,1024] fp32; Wq/Wk/Wv/Wo [1024,1024]; biases zero.
// out = softmax((xWq^T)(xWk^T)^T / 32) (xWv^T) Wo^T + bo   (16 heads, d=64)
//
// Pipeline (bf16 MFMA, fp32 accum):
//  k_cvt: x,W* fp32->bf16
//  k_gemm (global_load_lds width-16 staging, linear pow2 LDS, m97 recipe)
//  k_attn: flash-style, swapped-S^T MFMA (P lane-local along kv), 128B LDS
//    rows + XOR swizzle both-sides, DOUBLE-BUFFERED K/V prefetch (one
//    barrier/tile, drain overlapped with compute), den accumulated via
//    MFMA with an all-ones B fragment (no VALU adds, no final shuffles).
//    launch_bounds(256,4): (256,5) spilled accumulators in r4.

#define HID 1024
#define NH 16
#define HD 64
#define BB 4
#define SEQ 2048
#define MTOT (BB * SEQ) // 8192

typedef short bf16x8 __attribute__((ext_vector_type(8)));
typedef float f32x4 __attribute__((ext_vector_type(4)));

// swizzle: byte col within a 128B row, XORed by row&7 -> conflict-free b128
#define SWZ(row, cb) ((cb) ^ (((row) & 7) << 4))

#define GLDS(gp, lp) __builtin_amdgcn_global_load_lds( \
    (const __attribute__((address_space(1))) void*)(gp), \
    (__attribute__((address_space(3))) void*)(lp), 16, 0, 0)

static __device__ __forceinline__ unsigned short f2bf(float f) {
  unsigned u = __float_as_uint(f);
  u += 0x7fffu + ((u >> 16) & 1u); // RNE
  return (unsigned short)(u >> 16);
}

static __device__ __forceinline__ f32x4 mfma16(bf16x8 a, bf16x8 b, f32x4 c) {
  return __builtin_amdgcn_mfma_f32_16x16x32_bf16(a, b, c, 0, 0, 0);
}

// ---------------- fp32 -> bf16 convert ----------------
__global__ void k_cvt(const float* __restrict__ in, unsigned short* __restrict__ out, int n4) {
  int i = blockIdx.x * blockDim.x + threadIdx.x;
  if (i >= n4) return;
  float4 v = reinterpret_cast<const float4*>(in)[i];
  ushort4 o;
  o.x = f2bf(v.x); o.y = f2bf(v.y); o.z = f2bf(v.z); o.w = f2bf(v.w);
  reinterpret_cast<ushort4*>(out)[i] = o;
}

// ---------------- GEMM: C[8192,1024] = A[M,K] @ W[N,K]^T + bias ----------------
// 128x128 tile, BK=64, 4 waves (2x2). global_load_lds dwordx4 into LINEAR
// [128][64]-short LDS (m97 recipe).
#define MODE_QK 0
#define MODE_V 1
#define MODE_OUT 2

__global__ __launch_bounds__(256, 2) void k_gemm(
    const unsigned short* __restrict__ A,
    const unsigned short* __restrict__ W,
    const float* __restrict__ bias,
    void* __restrict__ Cout, int mode, float scale) {
  const int K = HID;
  __shared__ __align__(16) unsigned short sA[128 * 64];
  __shared__ __align__(16) unsigned short sB[128 * 64];
  const int m0 = blockIdx.x * 128;
  const int n0 = blockIdx.y * 128;
  const int tid = threadIdx.x;
  const int lane = tid & 63, wid = tid >> 6;
  const int wr = wid >> 1, wc = wid & 1;
  const int lr = lane & 15, lg = lane >> 4;

  f32x4 acc[4][4] = {};

  const unsigned short* gA = A + (size_t)m0 * K;
  const unsigned short* gW = W + (size_t)n0 * K;

  for (int kt = 0; kt < K; kt += 64) {
#pragma unroll
    for (int i = 0; i < 4; ++i) {
      int c = tid + i * 256;
      int row = c >> 3, col = (c & 7) << 3;
      GLDS(gA + (size_t)row * K + kt + col, (char*)sA + (size_t)c * 16);
      GLDS(gW + (size_t)row * K + kt + col, (char*)sB + (size_t)c * 16);
    }
    __syncthreads(); // drains vmcnt(0): staged data visible
#pragma unroll
    for (int kk = 0; kk < 64; kk += 32) {
      bf16x8 a[4], b[4];
      const int co = kk + lg * 8;
#pragma unroll
      for (int m = 0; m < 4; ++m)
        a[m] = *reinterpret_cast<const bf16x8*>(sA + (wr * 64 + m * 16 + lr) * 64 + co);
#pragma unroll
      for (int n = 0; n < 4; ++n)
        b[n] = *reinterpret_cast<const bf16x8*>(sB + (wc * 64 + n * 16 + lr) * 64 + co);
      __builtin_amdgcn_s_setprio(1);
#pragma unroll
      for (int m = 0; m < 4; ++m)
#pragma unroll
        for (int n = 0; n < 4; ++n)
          acc[m][n] = mfma16(a[m], b[n], acc[m][n]);
      __builtin_amdgcn_s_setprio(0);
    }
    __syncthreads();
  }

  if (mode == MODE_OUT) {
    float* C = (float*)Cout;
#pragma unroll
    for (int m = 0; m < 4; ++m) {
      int row0 = m0 + wr * 64 + m * 16 + lg * 4;
#pragma unroll
      for (int n = 0; n < 4; ++n) {
        int col = n0 + wc * 64 + n * 16 + lr;
        float bv = bias[col];
#pragma unroll
        for (int r = 0; r < 4; ++r)
          C[(size_t)(row0 + r) * HID + col] = acc[m][n][r] + bv;
      }
    }
  } else if (mode == MODE_QK) {
    unsigned short* C = (unsigned short*)Cout;
#pragma unroll
    for (int m = 0; m < 4; ++m) {
      int row0 = m0 + wr * 64 + m * 16 + lg * 4;
      int b = row0 >> 11;
#pragma unroll
      for (int n = 0; n < 4; ++n) {
        int col = n0 + wc * 64 + n * 16 + lr;
        float bv = bias[col];
        int h = col >> 6, d = col & 63;
        size_t base = ((size_t)(b * NH + h) * SEQ) * HD + d;
#pragma unroll
        for (int r = 0; r < 4; ++r) {
          int tok = (row0 + r) & 2047;
          C[base + (size_t)tok * HD] = f2bf((acc[m][n][r] + bv) * scale);
        }
      }
    }
  } else {
    unsigned short* C = (unsigned short*)Cout;
#pragma unroll
    for (int m = 0; m < 4; ++m) {
      int row0 = m0 + wr * 64 + m * 16 + lg * 4;
      int b = row0 >> 11;
      int tok0 = row0 & 2047;
#pragma unroll
      for (int n = 0; n < 4; ++n) {
        int col = n0 + wc * 64 + n * 16 + lr;
        float bv = bias[col];
        int h = col >> 6, d = col & 63;
        ushort4 pk;
        pk.x = f2bf(acc[m][n][0] + bv);
        pk.y = f2bf(acc[m][n][1] + bv);
        pk.z = f2bf(acc[m][n][2] + bv);
        pk.w = f2bf(acc[m][n][3] + bv);
        *reinterpret_cast<ushort4*>(&C[((size_t)(b * NH + h) * HD + d) * SEQ + tok0]) = pk;
      }
    }
  }
}

// ---------------- attention ----------------
// grid (bh=64, qt=16); 4 waves; wave owns 32 q-rows. KVB=64, K/V double-buffered.
// Per tile: prefetch(t+1 -> buf^1) issued FIRST, then S/P/PV on buf, then one
// __syncthreads() (vmcnt drain overlapped with compute). sP is per-wave-row
// private after the initial barrier (Q staging is cross-wave, P writes are not).
// den: accd[m] += mfma(pa[m], ones) -> same fragment layout as acco, no shuffles.
#define KVB 64

__global__ __launch_bounds__(256, 4) void k_attn(
    const unsigned short* __restrict__ Qg,  // [64][2048][64]
    const unsigned short* __restrict__ Kg,  // [64][2048][64]
    const unsigned short* __restrict__ Vt,  // [64][64][2048]
    unsigned short* __restrict__ Og) {      // [8192][1024] bf16
  __shared__ __align__(16) unsigned short sP[128 * 64];    // 16KB (Q staged here first)
  __shared__ __align__(16) unsigned short sK[2][KVB * 64]; // 16KB
  __shared__ __align__(16) unsigned short sV[2][KVB * 64]; // 16KB

  const int bh = blockIdx.x;
  const int qt = blockIdx.y;
  const int tid = threadIdx.x;
  const int lane = tid & 63, wid = tid >> 6;
  const int lr = lane & 15, lg = lane >> 4;

  const unsigned short* Qh = Qg + ((size_t)bh * SEQ + (size_t)qt * 128) * HD;
  const unsigned short* Kh = Kg + (size_t)bh * SEQ * HD;
  const unsigned short* Vh = Vt + (size_t)bh * HD * SEQ;

  // per-thread staging geometry (chunk c in [0,511] for K/V tiles)
  const int c0 = tid, c1 = tid + 256;
  const int r0 = c0 >> 3, r1 = c1 >> 3;
  const int cb0 = SWZ(r0, (c0 & 7) << 4) >> 1; // short offset in row (pre-swizzled src)
  const int cb1 = SWZ(r1, (c1 & 7) << 4) >> 1;

  // stage Q tile (128 rows x 128B): linear dest byte c*16, source pre-swizzled
#pragma unroll
  for (int i = 0; i < 4; ++i) {
    int c = tid + i * 256;
    int row = c >> 3;
    int cbl = SWZ(row, (c & 7) << 4);
    GLDS(Qh + (size_t)row * HD + (cbl >> 1), (char*)sP + (size_t)c * 16);
  }
  // prologue: stage K/V tile 0 into buffer 0
  GLDS(Kh + (size_t)r0 * HD + cb0, (char*)sK[0] + (size_t)c0 * 16);
  GLDS(Kh + (size_t)r1 * HD + cb1, (char*)sK[0] + (size_t)c1 * 16);
  GLDS(Vh + (size_t)r0 * SEQ + 0 + cb0, (char*)sV[0] + (size_t)c0 * 16);
  GLDS(Vh + (size_t)r1 * SEQ + 0 + cb1, (char*)sV[0] + (size_t)c1 * 16);
  __syncthreads(); // drains vmcnt: Q + tile0 visible

  bf16x8 qb[2][2];
#pragma unroll
  for (int m = 0; m < 2; ++m)
#pragma unroll
    for (int kd = 0; kd < 2; ++kd) {
      int row = wid * 32 + m * 16 + lr;
      qb[m][kd] = *reinterpret_cast<const bf16x8*>(
          (const char*)sP + row * 128 + SWZ(lr, kd * 64 + lg * 16));
    }
  // after this point sP is per-wave-row private (P writes/reads own rows only)

  const unsigned short onev = (unsigned short)0x3F80; // bf16 1.0
  const bf16x8 ones = {(short)onev, (short)onev, (short)onev, (short)onev,
                       (short)onev, (short)onev, (short)onev, (short)onev};

  f32x4 acco[2][4] = {};
  f32x4 accd[2] = {};

  for (int t = 0; t < SEQ / KVB; ++t) {
    const int cur = t & 1;
    // prefetch next tile into the other buffer (overlaps with compute below)
    if (t + 1 < SEQ / KVB) {
      const int ktn = (t + 1) * KVB;
      GLDS(Kh + (size_t)(ktn + r0) * HD + cb0, (char*)sK[cur ^ 1] + (size_t)c0 * 16);
      GLDS(Kh + (size_t)(ktn + r1) * HD + cb1, (char*)sK[cur ^ 1] + (size_t)c1 * 16);
      GLDS(Vh + (size_t)r0 * SEQ + ktn + cb0, (char*)sV[cur ^ 1] + (size_t)c0 * 16);
      GLDS(Vh + (size_t)r1 * SEQ + ktn + cb1, (char*)sV[cur ^ 1] + (size_t)c1 * 16);
    }

    // S^T = K Q^T : accs[m][n]: kv = n*16+4lg+r, q = wid*32+m*16+lr
    f32x4 accs[2][4] = {};
#pragma unroll
    for (int kd = 0; kd < 2; ++kd) {
      bf16x8 ka[4];
#pragma unroll
      for (int n = 0; n < 4; ++n)
        ka[n] = *reinterpret_cast<const bf16x8*>(
            (const char*)sK[cur] + (n * 16 + lr) * 128 + SWZ(lr, kd * 64 + lg * 16));
      __builtin_amdgcn_s_setprio(1);
#pragma unroll
      for (int n = 0; n < 4; ++n) {
        accs[0][n] = mfma16(ka[n], qb[0][kd], accs[0][n]);
        accs[1][n] = mfma16(ka[n], qb[1][kd], accs[1][n]);
      }
      __builtin_amdgcn_s_setprio(0);
    }

    // P = exp2(S^T) -> packed bf16 swizzled b64 write to sP[q][kv] (own rows)
#pragma unroll
    for (int m = 0; m < 2; ++m) {
      const int q = wid * 32 + m * 16 + lr;
#pragma unroll
      for (int n = 0; n < 4; ++n) {
        float p0 = exp2f(accs[m][n][0]);
        float p1 = exp2f(accs[m][n][1]);
        float p2 = exp2f(accs[m][n][2]);
        float p3 = exp2f(accs[m][n][3]);
        unsigned w0, w1;
        asm("v_cvt_pk_bf16_f32 %0, %1, %2" : "=v"(w0) : "v"(p0), "v"(p1));
        asm("v_cvt_pk_bf16_f32 %0, %1, %2" : "=v"(w1) : "v"(p2), "v"(p3));
        uint2 pk; pk.x = w0; pk.y = w1;
        *reinterpret_cast<uint2*>((char*)sP + q * 128 + SWZ(q, n * 32 + lg * 8)) = pk;
      }
    }

    // O += P V ; den += P * ones (same MFMA pipe, acco-layout result)
#pragma unroll
    for (int js = 0; js < 2; ++js) {
      bf16x8 pa[2], vb[4];
#pragma unroll
      for (int m = 0; m < 2; ++m) {
        int row = wid * 32 + m * 16 + lr;
        pa[m] = *reinterpret_cast<const bf16x8*>(
            (const char*)sP + row * 128 + SWZ(lr, js * 64 + lg * 16));
      }
#pragma unroll
      for (int n = 0; n < 4; ++n)
        vb[n] = *reinterpret_cast<const bf16x8*>(
            (const char*)sV[cur] + (n * 16 + lr) * 128 + SWZ(lr, js * 64 + lg * 16));
      __builtin_amdgcn_s_setprio(1);
#pragma unroll
      for (int m = 0; m < 2; ++m) {
#pragma unroll
        for (int n = 0; n < 4; ++n)
          acco[m][n] = mfma16(pa[m], vb[n], acco[m][n]);
        accd[m] = mfma16(pa[m], ones, accd[m]);
      }
      __builtin_amdgcn_s_setprio(0);
    }

    // single barrier per tile: drains prefetch (overlapped with the compute
    // above) and protects buf[cur] before it is re-staged at t+2.
    __syncthreads();
  }

  // rden directly from accd (identical fragment layout to acco)
  const int b = bh >> 4, h = bh & 15;
#pragma unroll
  for (int m = 0; m < 2; ++m) {
    int tok0 = qt * 128 + wid * 32 + m * 16 + lg * 4;
#pragma unroll
    for (int r = 0; r < 4; ++r) {
      float rd = 1.0f / accd[m][r];
#pragma unroll
      for (int n = 0; n < 4; ++n) {
        int col = h * 64 + n * 16 + lr;
        Og[(size_t)(b * SEQ + tok0 + r) * HID + col] = f2bf(acco[m][n][r] * rd);
      }
    }
  }
}

// ---------------- launch ----------------
extern "C" void kernel_launch(void* const* d_in, const int* in_sizes, int n_in,
                              void* d_out, int out_size, void* d_ws, size_t ws_size,
                              hipStream_t stream) {
  (void)in_sizes; (void)n_in; (void)out_size; (void)ws_size;
  const float* x = (const float*)d_in[0];
  const float* Wq = (const float*)d_in[1];
  const float* bq = (const float*)d_in[2];
  const float* Wk = (const float*)d_in[3];
  const float* bk = (const float*)d_in[4];
  const float* Wv = (const float*)d_in[5];
  const float* bv = (const float*)d_in[6];
  const float* Wo = (const float*)d_in[7];
  const float* bo = (const float*)d_in[8];

  unsigned short* ws = (unsigned short*)d_ws;
  unsigned short* xb = ws;
  unsigned short* wqb = xb + (size_t)MTOT * HID;
  unsigned short* wkb = wqb + (size_t)HID * HID;
  unsigned short* wvb = wkb + (size_t)HID * HID;
  unsigned short* wob = wvb + (size_t)HID * HID;
  unsigned short* qb = wob + (size_t)HID * HID;   // [64][2048][64]
  unsigned short* kb = qb + (size_t)MTOT * HID;   // [64][2048][64]
  unsigned short* vtb = kb + (size_t)MTOT * HID;  // [64][64][2048]
  unsigned short* ob = vtb + (size_t)MTOT * HID;  // [8192][1024]

  const float cexp = 0.04508422f; // log2(e)/32

  k_cvt<<<(MTOT * HID / 4) / 256, 256, 0, stream>>>(x, xb, MTOT * HID / 4);
  k_cvt<<<(HID * HID / 4) / 256, 256, 0, stream>>>(Wq, wqb, HID * HID / 4);
  k_cvt<<<(HID * HID / 4) / 256, 256, 0, stream>>>(Wk, wkb, HID * HID / 4);
  k_cvt<<<(HID * HID / 4) / 256, 256, 0, stream>>>(Wv, wvb, HID * HID / 4);
  k_cvt<<<(HID * HID / 4) / 256, 256, 0, stream>>>(Wo, wob, HID * HID / 4);

  dim3 gg(MTOT / 128, HID / 128); // 64 x 8
  k_gemm<<<gg, 256, 0, stream>>>(xb, wqb, bq, qb, MODE_QK, cexp);
  k_gemm<<<gg, 256, 0, stream>>>(xb, wkb, bk, kb, MODE_QK, 1.0f);
  k_gemm<<<gg, 256, 0, stream>>>(xb, wvb, bv, vtb, MODE_V, 1.0f);

  k_attn<<<dim3(64, SEQ / 128), 256, 0, stream>>>(qb, kb, vtb, ob);

  k_gemm<<<gg, 256, 0, stream>>>(ob, wob, bo, d_out, MODE_OUT, 1.0f);
}